// Round 4
// baseline (52.940 us; speedup 1.0000x reference)
//
#include <hip/hip_runtime.h>

// Problem constants (B=16384, D=1024, HARD_RATIO=0.3 -> K=4915)
constexpr int B_ROWS = 16384;
constexpr int K_HARD = 4915;           // max(1, int(16384 * 0.3))
constexpr float MARGIN_POS = 0.1f;
constexpr float MARGIN_NEG = 0.8f;

typedef float f32x4 __attribute__((ext_vector_type(4)));

// 12 in-flight float4 loads for one row (q/dp/dn x 4 chunks of 1KB).
struct RowRegs {
    f32x4 q0, q1, q2, q3, p0, p1, p2, p3, n0, n1, n2, n3;
};

__device__ __forceinline__ void issue12(RowRegs& r, unsigned vo,
                                        const float* __restrict__ q,
                                        const float* __restrict__ dp,
                                        const float* __restrict__ dn)
{
    asm volatile(
        "global_load_dwordx4 %[Q0], %[VO], %[QB] offset:0\n\t"
        "global_load_dwordx4 %[Q1], %[VO], %[QB] offset:1024\n\t"
        "global_load_dwordx4 %[Q2], %[VO], %[QB] offset:2048\n\t"
        "global_load_dwordx4 %[Q3], %[VO], %[QB] offset:3072\n\t"
        "global_load_dwordx4 %[P0], %[VO], %[PB] offset:0\n\t"
        "global_load_dwordx4 %[P1], %[VO], %[PB] offset:1024\n\t"
        "global_load_dwordx4 %[P2], %[VO], %[PB] offset:2048\n\t"
        "global_load_dwordx4 %[P3], %[VO], %[PB] offset:3072\n\t"
        "global_load_dwordx4 %[N0], %[VO], %[NB] offset:0\n\t"
        "global_load_dwordx4 %[N1], %[VO], %[NB] offset:1024\n\t"
        "global_load_dwordx4 %[N2], %[VO], %[NB] offset:2048\n\t"
        "global_load_dwordx4 %[N3], %[VO], %[NB] offset:3072"
        : [Q0]"=&v"(r.q0), [Q1]"=&v"(r.q1), [Q2]"=&v"(r.q2), [Q3]"=&v"(r.q3),
          [P0]"=&v"(r.p0), [P1]"=&v"(r.p1), [P2]"=&v"(r.p2), [P3]"=&v"(r.p3),
          [N0]"=&v"(r.n0), [N1]"=&v"(r.n1), [N2]"=&v"(r.n2), [N3]"=&v"(r.n3)
        : [VO]"v"(vo), [QB]"s"(q), [PB]"s"(dp), [NB]"s"(dn)
    );
}

// counted waits; sched_barrier(0) pins dependent VALU below the wait (rule #18)
#define WAITV12 do { asm volatile("s_waitcnt vmcnt(12)" ::: "memory"); \
                     __builtin_amdgcn_sched_barrier(0); } while (0)
#define WAITV0  do { asm volatile("s_waitcnt vmcnt(0)"  ::: "memory"); \
                     __builtin_amdgcn_sched_barrier(0); } while (0)

__device__ __forceinline__ void dot2(const RowRegs& r, float& sp, float& sn)
{
    float a = 0.f, b = 0.f;
#pragma unroll
    for (int c = 0; c < 4; ++c) {
        a += r.q0[c] * r.p0[c]; b += r.q0[c] * r.n0[c];
        a += r.q1[c] * r.p1[c]; b += r.q1[c] * r.n1[c];
        a += r.q2[c] * r.p2[c]; b += r.q2[c] * r.n2[c];
        a += r.q3[c] * r.p3[c]; b += r.q3[c] * r.n3[c];
    }
    sp = a; sn = b;
}

// ---------------------------------------------------------------------------
// Kernel 1: persistent grid-stride rowwise dots. 4096 waves x 4 rows each,
// depth-2 register pipeline, counted vmcnt waits, stores deferred to the end.
// Row stride between a wave's rows = 4096 rows = 16 MiB (fits 32-bit voff).
// ---------------------------------------------------------------------------
__global__ __launch_bounds__(256, 4) void dot_kernel(
    const float* __restrict__ q,
    const float* __restrict__ dp,
    const float* __restrict__ dn,
    float* __restrict__ out_pos,
    float* __restrict__ out_neg)
{
    const int NW   = 4096;                       // total waves
    const int wave = (blockIdx.x * blockDim.x + threadIdx.x) >> 6;
    const int lane = threadIdx.x & 63;

    const unsigned vo0  = (unsigned)wave * 4096u + (unsigned)lane * 16u;
    const unsigned step = (unsigned)NW * 4096u;  // 16 MiB

    RowRegs A, B;
    float sp0, sn0, sp1, sn1, sp2, sn2, sp3, sn3;

    issue12(A, vo0,            q, dp, dn);   // row0   -> out 12
    issue12(B, vo0 + step,     q, dp, dn);   // row1   -> out 24
    WAITV12;                                 // row0 ready
    dot2(A, sp0, sn0);
    issue12(A, vo0 + 2 * step, q, dp, dn);   // row2   -> out 24
    WAITV12;                                 // row1 ready
    dot2(B, sp1, sn1);
    issue12(B, vo0 + 3 * step, q, dp, dn);   // row3   -> out 24
    WAITV12;                                 // row2 ready
    dot2(A, sp2, sn2);
    WAITV0;                                  // row3 ready
    dot2(B, sp3, sn3);

    // wave reductions for all 4 rows
#pragma unroll
    for (int off = 32; off; off >>= 1) {
        sp0 += __shfl_xor(sp0, off); sn0 += __shfl_xor(sn0, off);
        sp1 += __shfl_xor(sp1, off); sn1 += __shfl_xor(sn1, off);
        sp2 += __shfl_xor(sp2, off); sn2 += __shfl_xor(sn2, off);
        sp3 += __shfl_xor(sp3, off); sn3 += __shfl_xor(sn3, off);
    }
    if (lane == 0) {
        out_pos[wave]          = sp0;  out_neg[wave]          = sn0;
        out_pos[wave + NW]     = sp1;  out_neg[wave + NW]     = sn1;
        out_pos[wave + 2*NW]   = sp2;  out_neg[wave + 2*NW]   = sn2;
        out_pos[wave + 3*NW]   = sp3;  out_neg[wave + 3*NW]   = sn3;
    }
}

// order-preserving float -> uint32 key (ascending float == ascending uint)
__device__ __forceinline__ unsigned f2key(float f) {
    unsigned u = __float_as_uint(f);
    return (u & 0x80000000u) ? ~u : (u | 0x80000000u);
}
__device__ __forceinline__ float key2f(unsigned k) {
    return __uint_as_float((k & 0x80000000u) ? (k & 0x7FFFFFFFu) : ~k);
}

// ---------------------------------------------------------------------------
// Kernel 2 (fused select + finalize): one 1024-thread block processes BOTH
// sides CONCURRENTLY (16 pos + 16 neg keys per thread, dual LDS histograms;
// wave 0 scans pos bins while wave 1 scans neg bins). Exact k-th order
// statistic via 4-round byte radix-select, then conditional sum with tie
// correction. Writes all 3 outputs.
// ---------------------------------------------------------------------------
__global__ __launch_bounds__(1024) void select_finalize_kernel(
    const float* __restrict__ ws_vals,   // [2*B]: pos then neg
    float* __restrict__ out)             // 3 floats
{
    __shared__ unsigned hist[2][256];
    __shared__ unsigned ebase[2][256];
    __shared__ unsigned s_prefix[2], s_m[2];
    __shared__ float    s_rf[2][16];
    __shared__ unsigned s_rc[2][16];

    const int tid  = threadIdx.x;
    const int lane = tid & 63;
    const int wid  = tid >> 6;

    const float4* vp = (const float4*)ws_vals;              // pos
    const float4* vn = (const float4*)(ws_vals + B_ROWS);   // neg

    unsigned kp[16], kn[16];
#pragma unroll
    for (int j = 0; j < 4; ++j) {
        const float4 a = vp[tid + j * 1024];
        const float4 b = vn[tid + j * 1024];
        kp[4*j+0] = f2key(a.x); kp[4*j+1] = f2key(a.y);
        kp[4*j+2] = f2key(a.z); kp[4*j+3] = f2key(a.w);
        kn[4*j+0] = f2key(b.x); kn[4*j+1] = f2key(b.y);
        kn[4*j+2] = f2key(b.z); kn[4*j+3] = f2key(b.w);
    }

    // target 0-based ascending ranks:
    //   pos: rank N-K (smallest member of top-K largest)
    //   neg: rank K-1 (largest member of bottom-K smallest)
    unsigned m0 = (unsigned)(B_ROWS - K_HARD), pre0 = 0;
    unsigned m1 = (unsigned)(K_HARD - 1),      pre1 = 0;

    for (int r = 0; r < 4; ++r) {
        const unsigned shift = 24 - 8 * r;
        const unsigned pmask = (r == 0) ? 0u : (0xFFFFFFFFu << (32 - 8 * r));
        if (tid < 256) { hist[0][tid] = 0; hist[1][tid] = 0; }
        __syncthreads();
#pragma unroll
        for (int j = 0; j < 16; ++j) {
            if ((kp[j] & pmask) == pre0) atomicAdd(&hist[0][(kp[j] >> shift) & 255u], 1u);
            if ((kn[j] & pmask) == pre1) atomicAdd(&hist[1][(kn[j] >> shift) & 255u], 1u);
        }
        __syncthreads();

        // wave 0 scans side 0, wave 1 scans side 1 (4 bins/lane, shfl_up scan)
        if (wid < 2) {
            const int s = wid;
            const unsigned h0 = hist[s][4*lane+0], h1 = hist[s][4*lane+1];
            const unsigned h2 = hist[s][4*lane+2], h3 = hist[s][4*lane+3];
            const unsigned g = h0 + h1 + h2 + h3;
            unsigned inc = g;
#pragma unroll
            for (int off = 1; off < 64; off <<= 1) {
                const unsigned t = __shfl_up(inc, off);
                if (lane >= off) inc += t;
            }
            const unsigned ex = inc - g;
            ebase[s][4*lane+0] = ex;
            ebase[s][4*lane+1] = ex + h0;
            ebase[s][4*lane+2] = ex + h0 + h1;
            ebase[s][4*lane+3] = ex + h0 + h1 + h2;
        }
        __syncthreads();

        if (tid < 512) {
            const int s = tid >> 8;
            const int b = tid & 255;
            const unsigned mm = s ? m1 : m0;
            const unsigned lo = ebase[s][b];
            const unsigned hi = lo + hist[s][b];
            if (lo <= mm && mm < hi) {      // exactly one bucket per side
                s_prefix[s] = (s ? pre1 : pre0) | ((unsigned)b << shift);
                s_m[s] = mm - lo;
            }
        }
        __syncthreads();
        pre0 = s_prefix[0]; m0 = s_m[0];
        pre1 = s_prefix[1]; m1 = s_m[1];
        // safe: hist/s_prefix next written only after 2+ more syncs
    }

    const unsigned tk0 = pre0, tk1 = pre1;   // exact k-th order statistics
    const float    tv0 = key2f(tk0), tv1 = key2f(tk1);

    float lp = 0.f, ln = 0.f;
    unsigned cp = 0, cn = 0;
#pragma unroll
    for (int j = 0; j < 16; ++j) {
        if (kp[j] > tk0) { lp += fmaxf(key2f(kp[j]) - MARGIN_POS, 0.f); cp++; }
        if (kn[j] < tk1) { ln += fmaxf(MARGIN_NEG - key2f(kn[j]), 0.f); cn++; }
    }
#pragma unroll
    for (int off = 32; off; off >>= 1) {
        lp += __shfl_xor(lp, off);  ln += __shfl_xor(ln, off);
        cp += __shfl_xor(cp, off);  cn += __shfl_xor(cn, off);
    }
    if (lane == 0) {
        s_rf[0][wid] = lp; s_rf[1][wid] = ln;
        s_rc[0][wid] = cp; s_rc[1][wid] = cn;
    }
    __syncthreads();
    if (tid == 0) {
        float tp = 0.f, tn = 0.f;
        unsigned ccp = 0, ccn = 0;
        for (int w = 0; w < 16; ++w) {
            tp += s_rf[0][w]; tn += s_rf[1][w];
            ccp += s_rc[0][w]; ccn += s_rc[1][w];
        }
        const float fp = fmaxf(tv0 - MARGIN_POS, 0.f);
        const float fn = fmaxf(MARGIN_NEG - tv1, 0.f);
        const float LP = (tp + (float)(K_HARD - (int)ccp) * fp) / (float)K_HARD;
        const float LN = (tn + (float)(K_HARD - (int)ccn) * fn) / (float)K_HARD;
        out[0] = LP + LN;
        out[1] = LP;
        out[2] = LN;
    }
}

extern "C" void kernel_launch(void* const* d_in, const int* in_sizes, int n_in,
                              void* d_out, int out_size, void* d_ws, size_t ws_size,
                              hipStream_t stream) {
    const float* q  = (const float*)d_in[0];   // q_neg_proj
    const float* dp = (const float*)d_in[1];   // d_pos
    const float* dn = (const float*)d_in[2];   // d_neg
    float* out = (float*)d_out;                // 3 floats

    float* ws     = (float*)d_ws;
    float* ws_pos = ws;                // [0, B)
    float* ws_neg = ws + B_ROWS;       // [B, 2B)

    // Kernel 1: 1024 blocks x 256 threads = 4096 waves x 4 rows each
    dot_kernel<<<1024, 256, 0, stream>>>(q, dp, dn, ws_pos, ws_neg);
    // Kernel 2: single block, both sides concurrently + finalize
    select_finalize_kernel<<<1, 1024, 0, stream>>>(ws_pos, out);
}